// Round 3
// baseline (436.944 us; speedup 1.0000x reference)
//
#include <hip/hip_runtime.h>

typedef float __attribute__((ext_vector_type(4))) f32x4;

// OUT[n, c=j*8+k, h, w] = sum_{a,m,b} W[j,a,m,b,k] * T[n,(j+a-1)*4+m, (h-1)%28, (w+b-2)%28]
//   T[n,cc,h,w] = x[n,cc,h,w] + x[n,cc+128,h,w]
//   (j+a-1) outside [0,32) -> zero (channel-group pad); (w+b-1) outside [0,28) -> zero (w pad)
//
// R3: software-pipelined row strip. One block per (n, 7-row chunk): grid = 128*4 = 512
//   = exactly 2 blocks/CU resident (32 KB LDS). Per row r: prefetch row r+1 into regs
//   (8x global_load_dwordx4, both halves) -> compute row r from LDS (84 ds_read_b128 +
//   1008 FMA/thread) -> sum halves in reg + 4x ds_write_b128 into alternate buffer ->
//   store outputs -> one barrier. HBM latency of r+1 hides under compute of r.
// LDS layout per row: T[ch][32] with quad-swizzle qpos = q ^ ((ch>>2)&7): the 8 j-groups
//   of a wave hit 8 distinct quad positions -> all 32 banks -> conflict-free (verified R2:
//   SQ_LDS_BANK_CONFLICT == 0). Pad position (qpos = s^7) is never read by compute.

#define ROWS 7
#define CHUNKS 4

__global__ __launch_bounds__(256, 2) void fused_shift_conv(
    const float* __restrict__ x, const float* __restrict__ Wt, float* __restrict__ out)
{
    __shared__ __align__(16) float T[2][4096];   // 2 x (128 ch x 32) = 32 KB

    const int blk   = blockIdx.x;
    const int n     = blk / CHUNKS;
    const int chunk = blk - n * CHUNKS;
    const int h0    = chunk * ROWS;

    const int t = threadIdx.x;

    // ---- per-thread staging geometry (row-invariant) ----
    // thread t owns T-row quads p = t + 256*i, i=0..3 (1024 quads = 128 ch x 8 qpos)
    int cofs[4];   // global float offset within one (n,:,h,:) plane: ch*784 + q*4
    int lofs[4];   // LDS float offset: p*4
    #pragma unroll
    for (int i = 0; i < 4; ++i) {
        const int p  = t + 256 * i;
        const int ch = p >> 3;
        const int qp = p & 7;
        int q = qp ^ ((ch >> 2) & 7);
        q = q > 6 ? 6 : q;            // pad slot: harmless dup of quad 6 (never read)
        cofs[i] = ch * 784 + q * 4;
        lofs[i] = p * 4;
    }

    const float* xn = x + (size_t)n * 200704;

    // ---- per-thread weights: thread t owns output channel c = t = j*8+k ----
    const int j = t >> 3;
    const int k = t & 7;
    float wr[3][4][3];
    {
        const float* wp = Wt + j * 288 + k;   // W[j,a,m,b,k] strides 288/96/24/8/1
        #pragma unroll
        for (int a = 0; a < 3; ++a)
            #pragma unroll
            for (int m = 0; m < 4; ++m)
                #pragma unroll
                for (int b = 0; b < 3; ++b)
                    wr[a][m][b] = wp[a * 96 + m * 24 + b * 8];
    }
    if (j == 0) {
        #pragma unroll
        for (int m = 0; m < 4; ++m)
            #pragma unroll
            for (int b = 0; b < 3; ++b) wr[0][m][b] = 0.f;
    }
    if (j == 31) {
        #pragma unroll
        for (int m = 0; m < 4; ++m)
            #pragma unroll
            for (int b = 0; b < 3; ++b) wr[2][m][b] = 0.f;
    }

    // ---- prologue: stage row 0 (h_src = h0-1 mod 28) ----
    {
        const float* base = xn + ((h0 + 27) % 28) * 28;
        #pragma unroll
        for (int i = 0; i < 4; ++i) {
            const f32x4 lo = *(const f32x4*)(base + cofs[i]);
            const f32x4 hi = *(const f32x4*)(base + cofs[i] + 100352);
            *(f32x4*)&T[0][lofs[i]] = lo + hi;
        }
    }
    __syncthreads();

    f32x4 lo[4], hi[4];
    for (int r = 0; r < ROWS; ++r) {
        // -- issue prefetch of row r+1 (h_src = h0+r, always < 28 here) --
        if (r < ROWS - 1) {
            const float* base = xn + (h0 + r) * 28;
            #pragma unroll
            for (int i = 0; i < 4; ++i) {
                lo[i] = *(const f32x4*)(base + cofs[i]);
                hi[i] = *(const f32x4*)(base + cofs[i] + 100352);
            }
        }

        // -- compute row r from T[r&1] --
        const float* Tb = T[r & 1];
        float acc[28];
        #pragma unroll
        for (int w = 0; w < 28; ++w) acc[w] = 0.f;

        #pragma unroll
        for (int a = 0; a < 3; ++a) {
            int g = j + a - 1;
            g = g < 0 ? 0 : (g > 31 ? 31 : g);   // weights already zeroed for OOB
            const int s = g & 7;
            #pragma unroll
            for (int m = 0; m < 4; ++m) {
                const int row = (g * 4 + m) * 32;
                const float w2 = wr[a][m][2];
                const float w1 = wr[a][m][1];
                const float w0 = wr[a][m][0];
                #pragma unroll
                for (int q = 0; q < 7; ++q) {
                    const f32x4 v = *(const f32x4*)&Tb[row + ((q ^ s) << 2)];
                    #pragma unroll
                    for (int e = 0; e < 4; ++e) {
                        const int wp_ = q * 4 + e;                          // source col w'
                        if (wp_ != 27) acc[wp_] += v[e] * w2;               // b=2 tap
                        acc[(wp_ + 1) % 28] += v[e] * w1;                   // b=1 tap
                        if (wp_ != 26) acc[(wp_ + 2) % 28] += v[e] * w0;    // b=0 tap
                    }
                }
            }
        }

        // -- land prefetch (compiler inserts the vmcnt wait here), stage into T[(r+1)&1] --
        if (r < ROWS - 1) {
            float* Td = T[(r + 1) & 1];
            #pragma unroll
            for (int i = 0; i < 4; ++i)
                *(f32x4*)&Td[lofs[i]] = lo[i] + hi[i];
        }

        // -- write OUT[n, t, h0+r, 0..27]: 7 aligned float4 stores --
        float* op = out + (size_t)n * 200704 + (size_t)t * 784 + (size_t)(h0 + r) * 28;
        #pragma unroll
        for (int qq = 0; qq < 7; ++qq) {
            f32x4 o;
            o.x = acc[qq * 4 + 0];
            o.y = acc[qq * 4 + 1];
            o.z = acc[qq * 4 + 2];
            o.w = acc[qq * 4 + 3];
            *(f32x4*)(op + qq * 4) = o;
        }

        __syncthreads();
    }
}

extern "C" void kernel_launch(void* const* d_in, const int* in_sizes, int n_in,
                              void* d_out, int out_size, void* d_ws, size_t ws_size,
                              hipStream_t stream) {
    const float* x  = (const float*)d_in[0];   // (128,256,28,28) f32
    const float* Wt = (const float*)d_in[1];   // (32,3,4,3,8)   f32
    float* out      = (float*)d_out;           // (128,256,28,28) f32

    const int nbatch = in_sizes[0] / 200704;   // 128
    const int grid   = nbatch * CHUNKS;        // 512 blocks = 2 resident per CU

    fused_shift_conv<<<grid, 256, 0, stream>>>(x, Wt, out);
}